// Round 2
// baseline (1281.264 us; speedup 1.0000x reference)
//
#include <hip/hip_runtime.h>
#include <hip/hip_bf16.h>
#include <math.h>
#include <stdint.h>

// Problem constants
#define DIM 4096
#define N_HEADS 32
#define N_KV_HEADS 8
#define HEAD_DIM 128
#define BSZ 2
#define SEQLEN 2048
#define BS (BSZ * SEQLEN)               // 4096 rows
#define KV_DIM (N_KV_HEADS * HEAD_DIM)  // 1024

typedef unsigned short u16;
typedef __attribute__((ext_vector_type(8))) short bf16x8;
typedef __attribute__((ext_vector_type(4))) float f32x4;
typedef __attribute__((ext_vector_type(8))) unsigned short u16x8;
typedef __attribute__((ext_vector_type(4))) unsigned short u16x4;

__device__ __forceinline__ u16 f2bf(float f) {
    __hip_bfloat16 h = __float2bfloat16(f);
    return *reinterpret_cast<u16*>(&h);
}
__device__ __forceinline__ float bf2f(u16 u) {
    __hip_bfloat16 h;
    *reinterpret_cast<u16*>(&h) = u;
    return __bfloat162float(h);
}

#define GLOAD_LDS16(gptr, lptr)                                                      \
    __builtin_amdgcn_global_load_lds(                                                \
        reinterpret_cast<const __attribute__((address_space(1))) uint32_t*>(         \
            reinterpret_cast<uintptr_t>(gptr)),                                      \
        reinterpret_cast<__attribute__((address_space(3))) uint32_t*>(               \
            reinterpret_cast<uintptr_t>(lptr)),                                      \
        16, 0, 0)

// ---------------------------------------------------------------------------
// cvt: fp32 -> bf16, 4 elems/thread
// ---------------------------------------------------------------------------
__global__ void cvt_f32_bf16(const float* __restrict__ in, u16* __restrict__ out, int n4) {
    int i = blockIdx.x * blockDim.x + threadIdx.x;
    if (i >= n4) return;
    float4 v = reinterpret_cast<const float4*>(in)[i];
    u16x4 o;
    o.x = f2bf(v.x); o.y = f2bf(v.y); o.z = f2bf(v.z); o.w = f2bf(v.w);
    reinterpret_cast<u16x4*>(out)[i] = o;
}

// ---------------------------------------------------------------------------
// transpose + cvt: in[K][N] fp32 -> out[N][K] bf16.  block (32,8), 32x32 tile.
// ---------------------------------------------------------------------------
__global__ __launch_bounds__(256) void transpose_f32_bf16(const float* __restrict__ in,
                                                          u16* __restrict__ out,
                                                          int K, int N) {
    __shared__ float tile[32][33];
    const int tx = threadIdx.x, ty = threadIdx.y;
    const int n0 = blockIdx.x * 32, k0 = blockIdx.y * 32;
#pragma unroll
    for (int i = 0; i < 4; ++i)
        tile[ty + 8 * i][tx] = in[(size_t)(k0 + ty + 8 * i) * N + n0 + tx];
    __syncthreads();
#pragma unroll
    for (int i = 0; i < 4; ++i)
        out[(size_t)(n0 + ty + 8 * i) * K + k0 + tx] = f2bf(tile[tx][ty + 8 * i]);
}

// ---------------------------------------------------------------------------
// transpose bf16 V into per-(b,hkv) head-major layout:
//   xv  [BS][KV_DIM]  (row = b*S + k, col = hkv*128 + d)
//   xvT [(b*8+hkv)*128 + d][SEQLEN]  (col = k)
// ---------------------------------------------------------------------------
__global__ __launch_bounds__(256) void transpose_v_bf16(const u16* __restrict__ xv,
                                                        u16* __restrict__ xvT) {
    __shared__ u16 tile[32][33];
    const int tx = threadIdx.x, ty = threadIdx.y;
    const int k0 = blockIdx.x * 32, d0 = blockIdx.y * 32;
    const int bh = blockIdx.z;
    const int b = bh >> 3, hkv = bh & 7;
#pragma unroll
    for (int i = 0; i < 4; ++i)
        tile[ty + 8 * i][tx] =
            xv[((size_t)(b * SEQLEN) + k0 + ty + 8 * i) * KV_DIM + hkv * HEAD_DIM + d0 + tx];
    __syncthreads();
#pragma unroll
    for (int i = 0; i < 4; ++i)
        xvT[((size_t)bh * HEAD_DIM + d0 + ty + 8 * i) * SEQLEN + k0 + tx] = tile[tx][ty + 8 * i];
}

// ---------------------------------------------------------------------------
// MFMA bf16 GEMM:  C[M,N] = A[M,K] @ B[K,N]  with B given TRANSPOSED (BT[N,K]).
// (unchanged — verified good)
// ---------------------------------------------------------------------------
template <bool OUT_BF16>
__global__ __launch_bounds__(256) void gemm_mfma_bt(const u16* __restrict__ A,
                                                    const u16* __restrict__ BT,
                                                    void* __restrict__ Cv,
                                                    int M, int N, int K) {
    __shared__ __align__(16) u16 Al[128 * 64];
    __shared__ __align__(16) u16 Bl[128 * 64];

    const int tid  = threadIdx.x;
    const int wave = tid >> 6;
    const int lane = tid & 63;
    const int quad = lane >> 4;
    const int lm   = lane & 15;
    const size_t bm = (size_t)blockIdx.y * 128;
    const size_t bn = (size_t)blockIdx.x * 128;
    const int wm = (wave & 1) * 64;
    const int wn = (wave >> 1) * 64;

    const int slot = lane & 7;
    const int lrow = lane >> 3;
    const int csw  = slot ^ (lrow & 7);

    f32x4 acc[4][4] = {};

    for (int k0 = 0; k0 < K; k0 += 64) {
        __syncthreads();
#pragma unroll
        for (int i = 0; i < 4; ++i) {
            const int mloc = wave * 32 + i * 8 + lrow;
            const u16* gA = A  + (bm + mloc) * (size_t)K + k0 + csw * 8;
            const u16* gB = BT + (bn + mloc) * (size_t)K + k0 + csw * 8;
            u16* lA = &Al[(mloc * 8 + slot) * 8];
            u16* lB = &Bl[(mloc * 8 + slot) * 8];
            GLOAD_LDS16(gA, lA);
            GLOAD_LDS16(gB, lB);
        }
        __syncthreads();

#pragma unroll
        for (int ks8 = 0; ks8 < 8; ks8 += 4) {
            bf16x8 af[4], bfr[4];
            const int cc = ks8 + quad;
#pragma unroll
            for (int i = 0; i < 4; ++i) {
                const int m = wm + 16 * i + lm;
                af[i]  = *(const bf16x8*)&Al[(m * 8 + (cc ^ (m & 7))) * 8];
                const int n = wn + 16 * i + lm;
                bfr[i] = *(const bf16x8*)&Bl[(n * 8 + (cc ^ (n & 7))) * 8];
            }
#pragma unroll
            for (int i = 0; i < 4; ++i)
#pragma unroll
                for (int j = 0; j < 4; ++j)
                    acc[i][j] = __builtin_amdgcn_mfma_f32_16x16x32_bf16(af[i], bfr[j], acc[i][j], 0, 0, 0);
        }
    }

#pragma unroll
    for (int i = 0; i < 4; ++i) {
        const int mrow = wm + 16 * i + quad * 4;
#pragma unroll
        for (int j = 0; j < 4; ++j) {
            const int ncol = wn + 16 * j + lm;
#pragma unroll
            for (int r = 0; r < 4; ++r) {
                const size_t off = (bm + mrow + r) * (size_t)N + bn + ncol;
                const float v = acc[i][j][r];
                if constexpr (OUT_BF16) ((u16*)Cv)[off] = f2bf(v);
                else                    ((float*)Cv)[off] = v;
            }
        }
    }
}

// ---------------------------------------------------------------------------
// RoPE (interleaved pairs), in-place on bf16. t layout: (BS, n_heads*128).
// ---------------------------------------------------------------------------
__global__ void rope_kernel(u16* __restrict__ t,
                            const float* __restrict__ cosb,
                            const float* __restrict__ sinb,
                            int n_heads, int total_pairs) {
    int idx = blockIdx.x * blockDim.x + threadIdx.x;
    if (idx >= total_pairs) return;
    int p = idx & 63;
    int h = (idx >> 6) % n_heads;
    int bs = idx / (64 * n_heads);
    int s = bs & (SEQLEN - 1);        // start_pos = 0

    float c = cosb[s * 64 + p];
    float sn = sinb[s * 64 + p];

    size_t base = (size_t)bs * (n_heads * HEAD_DIM) + h * HEAD_DIM + 2 * p;
    float e = bf2f(t[base]);
    float o = bf2f(t[base + 1]);
    t[base]     = f2bf(e * c - o * sn);
    t[base + 1] = f2bf(e * sn + o * c);
}

// ---------------------------------------------------------------------------
// MFMA flash attention (causal, online softmax), Q-tile 128.
//   grid (S/128, N_HEADS, BSZ), 256 threads = 4 waves.
//   Wave w owns q rows [128*qt + 32w, +32) as two 16-row fragment groups.
//   KV-tile 64. K staged row-major [64][128]; V staged transposed [128][64].
//   Each K/V fragment ds_read feeds TWO MFMAs (both q-groups) -> LDS-pipe
//   and staging/barrier cost per unit work halved vs Q-tile 64.
//   Softmax in raw-score domain; scale*log2e folded into exp2f args.
//   Heavy tiles launched first (qt reversed) to shrink the imbalance tail.
// Fragment layouts (verified):
//   A: row = lane&15, k = (lane>>4)*8 + j ;  B: k = (lane>>4)*8 + j, col = lane&15
//   C: col = lane&15, row = (lane>>4)*4 + r
// ---------------------------------------------------------------------------
__global__ __launch_bounds__(256) void flash_attn_mfma(const u16* __restrict__ xq,
                                                       const u16* __restrict__ xk,
                                                       const u16* __restrict__ xvT,
                                                       u16* __restrict__ ctx) {
    __shared__ __align__(16) u16 Ks[64 * 16 * 8];     // 16 KB
    __shared__ __align__(16) u16 Vt[128 * 8 * 8];     // 16 KB
    __shared__ __align__(16) u16 Ps[4][32 * 8 * 8];   // 16 KB: per-wave P, 32 q rows

    const int qt  = (int)gridDim.x - 1 - (int)blockIdx.x;  // heavy-first
    const int h   = blockIdx.y;
    const int b   = blockIdx.z;
    const int hkv = h >> 2;

    const int tid  = threadIdx.x;
    const int wave = tid >> 6;
    const int lane = tid & 63;
    const int quad = lane >> 4;
    const int lm   = lane & 15;
    const int q0   = qt * 128;
    const int wq0  = q0 + wave * 32;
    const float C = 0.08838834764831845f * 1.44269504088896f;  // (1/sqrt(128))*log2(e)

    // Q fragments: group g rows wq0 + g*16 + lm
    bf16x8 qf[2][4];
#pragma unroll
    for (int g = 0; g < 2; ++g) {
        const u16* qp = xq + ((size_t)(b * SEQLEN) + wq0 + g * 16 + lm) * DIM
                        + h * HEAD_DIM + quad * 8;
#pragma unroll
        for (int s = 0; s < 4; ++s) qf[g][s] = *(const bf16x8*)(qp + s * 32);
    }

    float m_i[2][4], l_i[2][4];
#pragma unroll
    for (int g = 0; g < 2; ++g)
#pragma unroll
        for (int r = 0; r < 4; ++r) { m_i[g][r] = -INFINITY; l_i[g][r] = 0.f; }
    f32x4 acc_o[2][8] = {};

    const int nkt = 2 * qt + 2;
    for (int kt = 0; kt < nkt; ++kt) {
        const int k0 = kt * 64;
        __syncthreads();
        // --- stage K [64][128] and V^T [128][64] (chunk-XOR pre-swizzled src) ---
#pragma unroll
        for (int i = 0; i < 4; ++i) {
            const int ci = i * 256 + tid;              // 0..1023 chunk index
            const int kr = ci >> 4, cp = ci & 15;
            const u16* gK = xk + ((size_t)(b * SEQLEN + k0 + kr)) * KV_DIM
                            + hkv * HEAD_DIM + (cp ^ (kr & 7)) * 8;
            GLOAD_LDS16(gK, &Ks[ci * 8]);
            const int dr = ci >> 3, cq = ci & 7;
            const u16* gV = xvT + (((size_t)(b * N_KV_HEADS + hkv)) * HEAD_DIM + dr) * SEQLEN
                            + k0 + (cq ^ (dr & 7)) * 8;
            GLOAD_LDS16(gV, &Vt[ci * 8]);
        }
        __syncthreads();

        if (k0 > wq0 + 31) continue;   // this wave's rows all < k0: fully masked tile

        // --- QK^T: S[32 q][64 k] per wave; each kf feeds both q-groups ---
        f32x4 sacc[2][4] = {};
        __builtin_amdgcn_s_setprio(1);
#pragma unroll
        for (int ks = 0; ks < 4; ++ks) {
#pragma unroll
            for (int ct = 0; ct < 4; ++ct) {
                const int krow = ct * 16 + lm;
                bf16x8 kf = *(const bf16x8*)&Ks[(krow * 16 + ((ks * 4 + quad) ^ (krow & 7))) * 8];
                sacc[0][ct] = __builtin_amdgcn_mfma_f32_16x16x32_bf16(qf[0][ks], kf, sacc[0][ct], 0, 0, 0);
                sacc[1][ct] = __builtin_amdgcn_mfma_f32_16x16x32_bf16(qf[1][ks], kf, sacc[1][ct], 0, 0, 0);
            }
        }
        __builtin_amdgcn_s_setprio(0);

        // --- causal mask (raw-score domain) ---
#pragma unroll
        for (int g = 0; g < 2; ++g) {
            if (k0 + 63 > wq0 + g * 16) {
#pragma unroll
                for (int ct = 0; ct < 4; ++ct)
#pragma unroll
                    for (int r = 0; r < 4; ++r)
                        if (k0 + ct * 16 + lm > wq0 + g * 16 + quad * 4 + r)
                            sacc[g][ct][r] = -1e30f;
            }
        }

        // --- online softmax (per quad: 16-lane row reduce) ---
        float alpha[2][4];
#pragma unroll
        for (int g = 0; g < 2; ++g)
#pragma unroll
            for (int r = 0; r < 4; ++r) {
                float mx = fmaxf(fmaxf(sacc[g][0][r], sacc[g][1][r]),
                                 fmaxf(sacc[g][2][r], sacc[g][3][r]));
#pragma unroll
                for (int off = 1; off < 16; off <<= 1) mx = fmaxf(mx, __shfl_xor(mx, off));
                const float nm = fmaxf(m_i[g][r], mx);
                alpha[g][r] = exp2f((m_i[g][r] - nm) * C);
                m_i[g][r] = nm;
                float sum = 0.f;
#pragma unroll
                for (int ct = 0; ct < 4; ++ct) {
                    const float p = exp2f((sacc[g][ct][r] - nm) * C);
                    sacc[g][ct][r] = p;
                    sum += p;
                }
#pragma unroll
                for (int off = 1; off < 16; off <<= 1) sum += __shfl_xor(sum, off);
                l_i[g][r] = alpha[g][r] * l_i[g][r] + sum;
            }

        // --- P: C-layout -> A-layout via per-wave swizzled LDS scratch ---
        u16* ps = &Ps[wave][0];
#pragma unroll
        for (int g = 0; g < 2; ++g)
#pragma unroll
            for (int ct = 0; ct < 4; ++ct)
#pragma unroll
                for (int r = 0; r < 4; ++r) {
                    const int qq  = g * 16 + quad * 4 + r;
                    const int col = ct * 16 + lm;
                    ps[(qq * 8 + ((col >> 3) ^ (qq & 7))) * 8 + (col & 7)] = f2bf(sacc[g][ct][r]);
                }
        bf16x8 pf[2][2];
#pragma unroll
        for (int g = 0; g < 2; ++g) {
            const int qq = g * 16 + lm;
#pragma unroll
            for (int ks = 0; ks < 2; ++ks)
                pf[g][ks] = *(const bf16x8*)&ps[(qq * 8 + ((ks * 4 + quad) ^ (qq & 7))) * 8];
        }

        // --- rescale O, then PV (each vf feeds both q-groups) ---
#pragma unroll
        for (int g = 0; g < 2; ++g)
#pragma unroll
            for (int dt = 0; dt < 8; ++dt)
#pragma unroll
                for (int r = 0; r < 4; ++r) acc_o[g][dt][r] *= alpha[g][r];

        __builtin_amdgcn_s_setprio(1);
#pragma unroll
        for (int ks = 0; ks < 2; ++ks)
#pragma unroll
            for (int dt = 0; dt < 8; ++dt) {
                const int d = dt * 16 + lm;
                bf16x8 vf = *(const bf16x8*)&Vt[(d * 8 + ((ks * 4 + quad) ^ (d & 7))) * 8];
                acc_o[0][dt] = __builtin_amdgcn_mfma_f32_16x16x32_bf16(pf[0][ks], vf, acc_o[0][dt], 0, 0, 0);
                acc_o[1][dt] = __builtin_amdgcn_mfma_f32_16x16x32_bf16(pf[1][ks], vf, acc_o[1][dt], 0, 0, 0);
            }
        __builtin_amdgcn_s_setprio(0);
    }

    // --- epilogue ---
#pragma unroll
    for (int g = 0; g < 2; ++g) {
        float inv_l[4];
#pragma unroll
        for (int r = 0; r < 4; ++r) inv_l[r] = 1.f / l_i[g][r];
        u16* op = ctx + ((size_t)(b * SEQLEN) + wq0 + g * 16 + quad * 4) * DIM + h * HEAD_DIM + lm;
#pragma unroll
        for (int r = 0; r < 4; ++r)
#pragma unroll
            for (int dt = 0; dt < 8; ++dt)
                op[(size_t)r * DIM + dt * 16] = f2bf(acc_o[g][dt][r] * inv_l[r]);
    }
}

// ---------------------------------------------------------------------------
// kernel_launch
// ---------------------------------------------------------------------------
extern "C" void kernel_launch(void* const* d_in, const int* in_sizes, int n_in,
                              void* d_out, int out_size, void* d_ws, size_t ws_size,
                              hipStream_t stream) {
    const float* x   = (const float*)d_in[0];
    const float* wq  = (const float*)d_in[1];
    const float* wk  = (const float*)d_in[2];
    const float* wv  = (const float*)d_in[3];
    const float* wo  = (const float*)d_in[4];
    const float* fc  = (const float*)d_in[5];
    const float* fs  = (const float*)d_in[6];
    float* out = (float*)d_out;

    // ws carve-up: exactly 160 MiB total
    u16* x_bf = (u16*)d_ws;                       // [4096][4096]
    u16* wqT  = x_bf + (size_t)BS * DIM;          // [4096][4096]
    u16* wkT  = wqT + (size_t)DIM * DIM;          // [1024][4096]
    u16* wvT  = wkT + (size_t)KV_DIM * DIM;       // [1024][4096]
    u16* woT  = wvT + (size_t)KV_DIM * DIM;       // [4096][4096]
    u16* xq   = woT + (size_t)DIM * DIM;          // [4096][4096]
    u16* xk   = xq + (size_t)BS * DIM;            // [4096][1024]
    u16* xv   = xk + (size_t)BS * KV_DIM;         // [4096][1024]
    u16* ctx  = x_bf;                             // alias x_bf (dead after QKV GEMMs)
    u16* xvT  = wvT;                              // alias wvT (dead after V projection)

    // 0) converts
    {
        int n4 = BS * DIM / 4;
        cvt_f32_bf16<<<(n4 + 255) / 256, 256, 0, stream>>>(x, x_bf, n4);
        dim3 blk(32, 8);
        transpose_f32_bf16<<<dim3(DIM / 32, DIM / 32), blk, 0, stream>>>(wq, wqT, DIM, DIM);
        transpose_f32_bf16<<<dim3(KV_DIM / 32, DIM / 32), blk, 0, stream>>>(wk, wkT, DIM, KV_DIM);
        transpose_f32_bf16<<<dim3(KV_DIM / 32, DIM / 32), blk, 0, stream>>>(wv, wvT, DIM, KV_DIM);
        transpose_f32_bf16<<<dim3(DIM / 32, DIM / 32), blk, 0, stream>>>(wo, woT, DIM, DIM);
    }

    // 1) QKV projections (MFMA)
    gemm_mfma_bt<true><<<dim3(DIM / 128, BS / 128), 256, 0, stream>>>(x_bf, wqT, xq, BS, DIM, DIM);
    gemm_mfma_bt<true><<<dim3(KV_DIM / 128, BS / 128), 256, 0, stream>>>(x_bf, wkT, xk, BS, KV_DIM, DIM);
    gemm_mfma_bt<true><<<dim3(KV_DIM / 128, BS / 128), 256, 0, stream>>>(x_bf, wvT, xv, BS, KV_DIM, DIM);

    // 1b) V -> head-major transposed layout (overwrites dead wvT)
    transpose_v_bf16<<<dim3(SEQLEN / 32, HEAD_DIM / 32, BSZ * N_KV_HEADS), dim3(32, 8), 0, stream>>>(xv, xvT);

    // 2) RoPE (Q and K only)
    {
        int total_q = BS * N_HEADS * 64;
        rope_kernel<<<(total_q + 255) / 256, 256, 0, stream>>>(xq, fc, fs, N_HEADS, total_q);
        int total_k = BS * N_KV_HEADS * 64;
        rope_kernel<<<(total_k + 255) / 256, 256, 0, stream>>>(xk, fc, fs, N_KV_HEADS, total_k);
    }

    // 3) MFMA flash attention (Q-tile 128) -> bf16 ctx
    flash_attn_mfma<<<dim3(SEQLEN / 128, N_HEADS, BSZ), 256, 0, stream>>>(xq, xk, xvT, ctx);

    // 4) Output projection (MFMA) -> fp32 out
    gemm_mfma_bt<false><<<dim3(DIM / 128, BS / 128), 256, 0, stream>>>(ctx, woT, out, BS, DIM, DIM);
}

// Round 3
// 1133.051 us; speedup vs baseline: 1.1308x; 1.1308x over previous
//
#include <hip/hip_runtime.h>
#include <hip/hip_bf16.h>
#include <math.h>
#include <stdint.h>

// Problem constants
#define DIM 4096
#define N_HEADS 32
#define N_KV_HEADS 8
#define HEAD_DIM 128
#define BSZ 2
#define SEQLEN 2048
#define BS (BSZ * SEQLEN)               // 4096 rows
#define KV_DIM (N_KV_HEADS * HEAD_DIM)  // 1024

typedef unsigned short u16;
typedef __attribute__((ext_vector_type(8))) short bf16x8;
typedef __attribute__((ext_vector_type(4))) float f32x4;
typedef __attribute__((ext_vector_type(8))) unsigned short u16x8;
typedef __attribute__((ext_vector_type(4))) unsigned short u16x4;

__device__ __forceinline__ u16 f2bf(float f) {
    __hip_bfloat16 h = __float2bfloat16(f);
    return *reinterpret_cast<u16*>(&h);
}
__device__ __forceinline__ float bf2f(u16 u) {
    __hip_bfloat16 h;
    *reinterpret_cast<u16*>(&h) = u;
    return __bfloat162float(h);
}

#define GLOAD_LDS16(gptr, lptr)                                                      \
    __builtin_amdgcn_global_load_lds(                                                \
        reinterpret_cast<const __attribute__((address_space(1))) uint32_t*>(         \
            reinterpret_cast<uintptr_t>(gptr)),                                      \
        reinterpret_cast<__attribute__((address_space(3))) uint32_t*>(               \
            reinterpret_cast<uintptr_t>(lptr)),                                      \
        16, 0, 0)

// ---------------------------------------------------------------------------
// cvt: fp32 -> bf16, 4 elems/thread
// ---------------------------------------------------------------------------
__global__ void cvt_f32_bf16(const float* __restrict__ in, u16* __restrict__ out, int n4) {
    int i = blockIdx.x * blockDim.x + threadIdx.x;
    if (i >= n4) return;
    float4 v = reinterpret_cast<const float4*>(in)[i];
    u16x4 o;
    o.x = f2bf(v.x); o.y = f2bf(v.y); o.z = f2bf(v.z); o.w = f2bf(v.w);
    reinterpret_cast<u16x4*>(out)[i] = o;
}

// ---------------------------------------------------------------------------
// transpose + cvt: in[K][N] fp32 -> out[N][K] bf16.  block (32,8), 32x32 tile.
// ---------------------------------------------------------------------------
__global__ __launch_bounds__(256) void transpose_f32_bf16(const float* __restrict__ in,
                                                          u16* __restrict__ out,
                                                          int K, int N) {
    __shared__ float tile[32][33];
    const int tx = threadIdx.x, ty = threadIdx.y;
    const int n0 = blockIdx.x * 32, k0 = blockIdx.y * 32;
#pragma unroll
    for (int i = 0; i < 4; ++i)
        tile[ty + 8 * i][tx] = in[(size_t)(k0 + ty + 8 * i) * N + n0 + tx];
    __syncthreads();
#pragma unroll
    for (int i = 0; i < 4; ++i)
        out[(size_t)(n0 + ty + 8 * i) * K + k0 + tx] = f2bf(tile[tx][ty + 8 * i]);
}

// ---------------------------------------------------------------------------
// transpose bf16 V into per-(b,hkv) head-major layout:
//   xv  [BS][KV_DIM]  (row = b*S + k, col = hkv*128 + d)
//   xvT [(b*8+hkv)*128 + d][SEQLEN]  (col = k)
// ---------------------------------------------------------------------------
__global__ __launch_bounds__(256) void transpose_v_bf16(const u16* __restrict__ xv,
                                                        u16* __restrict__ xvT) {
    __shared__ u16 tile[32][33];
    const int tx = threadIdx.x, ty = threadIdx.y;
    const int k0 = blockIdx.x * 32, d0 = blockIdx.y * 32;
    const int bh = blockIdx.z;
    const int b = bh >> 3, hkv = bh & 7;
#pragma unroll
    for (int i = 0; i < 4; ++i)
        tile[ty + 8 * i][tx] =
            xv[((size_t)(b * SEQLEN) + k0 + ty + 8 * i) * KV_DIM + hkv * HEAD_DIM + d0 + tx];
    __syncthreads();
#pragma unroll
    for (int i = 0; i < 4; ++i)
        xvT[((size_t)bh * HEAD_DIM + d0 + ty + 8 * i) * SEQLEN + k0 + tx] = tile[tx][ty + 8 * i];
}

// ---------------------------------------------------------------------------
// MFMA bf16 GEMM:  C[M,N] = A[M,K] @ B[K,N]  with B given TRANSPOSED (BT[N,K]).
// (unchanged — verified good)
// ---------------------------------------------------------------------------
template <bool OUT_BF16>
__global__ __launch_bounds__(256) void gemm_mfma_bt(const u16* __restrict__ A,
                                                    const u16* __restrict__ BT,
                                                    void* __restrict__ Cv,
                                                    int M, int N, int K) {
    __shared__ __align__(16) u16 Al[128 * 64];
    __shared__ __align__(16) u16 Bl[128 * 64];

    const int tid  = threadIdx.x;
    const int wave = tid >> 6;
    const int lane = tid & 63;
    const int quad = lane >> 4;
    const int lm   = lane & 15;
    const size_t bm = (size_t)blockIdx.y * 128;
    const size_t bn = (size_t)blockIdx.x * 128;
    const int wm = (wave & 1) * 64;
    const int wn = (wave >> 1) * 64;

    const int slot = lane & 7;
    const int lrow = lane >> 3;
    const int csw  = slot ^ (lrow & 7);

    f32x4 acc[4][4] = {};

    for (int k0 = 0; k0 < K; k0 += 64) {
        __syncthreads();
#pragma unroll
        for (int i = 0; i < 4; ++i) {
            const int mloc = wave * 32 + i * 8 + lrow;
            const u16* gA = A  + (bm + mloc) * (size_t)K + k0 + csw * 8;
            const u16* gB = BT + (bn + mloc) * (size_t)K + k0 + csw * 8;
            u16* lA = &Al[(mloc * 8 + slot) * 8];
            u16* lB = &Bl[(mloc * 8 + slot) * 8];
            GLOAD_LDS16(gA, lA);
            GLOAD_LDS16(gB, lB);
        }
        __syncthreads();

#pragma unroll
        for (int ks8 = 0; ks8 < 8; ks8 += 4) {
            bf16x8 af[4], bfr[4];
            const int cc = ks8 + quad;
#pragma unroll
            for (int i = 0; i < 4; ++i) {
                const int m = wm + 16 * i + lm;
                af[i]  = *(const bf16x8*)&Al[(m * 8 + (cc ^ (m & 7))) * 8];
                const int n = wn + 16 * i + lm;
                bfr[i] = *(const bf16x8*)&Bl[(n * 8 + (cc ^ (n & 7))) * 8];
            }
#pragma unroll
            for (int i = 0; i < 4; ++i)
#pragma unroll
                for (int j = 0; j < 4; ++j)
                    acc[i][j] = __builtin_amdgcn_mfma_f32_16x16x32_bf16(af[i], bfr[j], acc[i][j], 0, 0, 0);
        }
    }

#pragma unroll
    for (int i = 0; i < 4; ++i) {
        const int mrow = wm + 16 * i + quad * 4;
#pragma unroll
        for (int j = 0; j < 4; ++j) {
            const int ncol = wn + 16 * j + lm;
#pragma unroll
            for (int r = 0; r < 4; ++r) {
                const size_t off = (bm + mrow + r) * (size_t)N + bn + ncol;
                const float v = acc[i][j][r];
                if constexpr (OUT_BF16) ((u16*)Cv)[off] = f2bf(v);
                else                    ((float*)Cv)[off] = v;
            }
        }
    }
}

// ---------------------------------------------------------------------------
// RoPE (interleaved pairs), in-place on bf16. t layout: (BS, n_heads*128).
// ---------------------------------------------------------------------------
__global__ void rope_kernel(u16* __restrict__ t,
                            const float* __restrict__ cosb,
                            const float* __restrict__ sinb,
                            int n_heads, int total_pairs) {
    int idx = blockIdx.x * blockDim.x + threadIdx.x;
    if (idx >= total_pairs) return;
    int p = idx & 63;
    int h = (idx >> 6) % n_heads;
    int bs = idx / (64 * n_heads);
    int s = bs & (SEQLEN - 1);        // start_pos = 0

    float c = cosb[s * 64 + p];
    float sn = sinb[s * 64 + p];

    size_t base = (size_t)bs * (n_heads * HEAD_DIM) + h * HEAD_DIM + 2 * p;
    float e = bf2f(t[base]);
    float o = bf2f(t[base + 1]);
    t[base]     = f2bf(e * c - o * sn);
    t[base + 1] = f2bf(e * sn + o * c);
}

// ---------------------------------------------------------------------------
// MFMA flash attention (causal, online softmax), Q-tile 64, DOUBLE-BUFFERED.
//   grid (S/64, N_HEADS, BSZ), 256 threads = 4 waves; wave w owns q rows
//   [64*qt + 16w, +16), Q frags in registers.
//   2-phase pipeline (T3 minimum recipe): stage tile kt+1 into buf[sel^1]
//   BEFORE computing tile kt from buf[sel]; ONE vmcnt(0)+barrier per tile
//   (the __syncthreads at loop bottom). Stage latency hides under compute.
//   K staged row-major [64][128]; V staged transposed [128][64]; both via
//   global_load_lds w=16 with chunk-XOR pre-swizzled GLOBAL source (LDS
//   dest linear) -> fragment ds_read_b128 conflict-free.
//   Softmax in raw-score domain, scale*log2e folded into exp2f.
//   Heavy tiles first (qt reversed) to shrink the triangular-imbalance tail.
// Fragment layouts (verified):
//   A: row = lane&15, k = (lane>>4)*8 + j ;  B: k = (lane>>4)*8 + j, col = lane&15
//   C: col = lane&15, row = (lane>>4)*4 + r
// ---------------------------------------------------------------------------
__global__ __launch_bounds__(256) void flash_attn_mfma(const u16* __restrict__ xq,
                                                       const u16* __restrict__ xk,
                                                       const u16* __restrict__ xvT,
                                                       u16* __restrict__ ctx) {
    __shared__ __align__(16) u16 Ks[2][64 * 16 * 8];   // 2 x 16 KB
    __shared__ __align__(16) u16 Vt[2][128 * 8 * 8];   // 2 x 16 KB
    __shared__ __align__(16) u16 Ps[4][16 * 8 * 8];    // 8 KB per-wave P scratch

    const int qt  = (int)gridDim.x - 1 - (int)blockIdx.x;  // heavy-first
    const int h   = blockIdx.y;
    const int b   = blockIdx.z;
    const int hkv = h >> 2;

    const int tid  = threadIdx.x;
    const int wave = tid >> 6;
    const int lane = tid & 63;
    const int quad = lane >> 4;
    const int lm   = lane & 15;
    const int q0   = qt * 64;
    const float C = 0.08838834764831845f * 1.44269504088896f;  // (1/sqrt(128))*log2(e)

    // staging geometry precompute (per thread, shared by K and V paths)
    const int ciK_r[4] = { (0 * 256 + tid) >> 4, (1 * 256 + tid) >> 4,
                           (2 * 256 + tid) >> 4, (3 * 256 + tid) >> 4 };

    // Q fragments: rows q0 + wave*16 + lm
    bf16x8 qf[4];
    {
        const u16* qp = xq + ((size_t)(b * SEQLEN) + q0 + wave * 16 + lm) * DIM
                        + h * HEAD_DIM + quad * 8;
#pragma unroll
        for (int s = 0; s < 4; ++s) qf[s] = *(const bf16x8*)(qp + s * 32);
    }

    const u16* xkb = xk + (size_t)(b * SEQLEN) * KV_DIM + hkv * HEAD_DIM;
    const u16* xvb = xvT + ((size_t)(b * N_KV_HEADS + hkv)) * HEAD_DIM * SEQLEN;

    // stage tile kt into buffer sel
    auto STAGE = [&](int kt, int sel) {
        const int k0 = kt * 64;
#pragma unroll
        for (int i = 0; i < 4; ++i) {
            const int ci = i * 256 + tid;            // 0..1023 chunk index
            const int kr = ci >> 4, cp = ci & 15;
            const u16* gK = xkb + (size_t)(k0 + kr) * KV_DIM + (cp ^ (kr & 7)) * 8;
            GLOAD_LDS16(gK, &Ks[sel][ci * 8]);
            const int dr = ci >> 3, cq = ci & 7;
            const u16* gV = xvb + (size_t)dr * SEQLEN + k0 + (cq ^ (dr & 7)) * 8;
            GLOAD_LDS16(gV, &Vt[sel][ci * 8]);
        }
    };

    float m_i[4], l_i[4];
#pragma unroll
    for (int r = 0; r < 4; ++r) { m_i[r] = -INFINITY; l_i[r] = 0.f; }
    f32x4 acc_o[8] = {};

    STAGE(0, 0);
    __syncthreads();                                  // drains vmcnt(0) too

    for (int kt = 0; kt <= qt; ++kt) {
        const int sel = kt & 1;
        const int k0 = kt * 64;
        if (kt < qt) STAGE(kt + 1, sel ^ 1);          // prefetch next tile

        // --- QK^T: S[16 q][64 k] per wave, 16 MFMA ---
        const u16* ksb = &Ks[sel][0];
        const u16* vtb = &Vt[sel][0];
        f32x4 sacc[4] = {};
        __builtin_amdgcn_s_setprio(1);
#pragma unroll
        for (int ks = 0; ks < 4; ++ks) {
#pragma unroll
            for (int ct = 0; ct < 4; ++ct) {
                const int krow = ct * 16 + lm;
                bf16x8 kf = *(const bf16x8*)&ksb[(krow * 16 + ((ks * 4 + quad) ^ (krow & 7))) * 8];
                sacc[ct] = __builtin_amdgcn_mfma_f32_16x16x32_bf16(qf[ks], kf, sacc[ct], 0, 0, 0);
            }
        }
        __builtin_amdgcn_s_setprio(0);

        if (kt == qt) {  // causal mask on the diagonal tile (raw-score domain)
#pragma unroll
            for (int ct = 0; ct < 4; ++ct)
#pragma unroll
                for (int r = 0; r < 4; ++r)
                    if (k0 + ct * 16 + lm > q0 + wave * 16 + quad * 4 + r)
                        sacc[ct][r] = -1e30f;
        }

        // --- online softmax: row-reduce across the 16 lanes of each quad ---
        float alpha[4];
#pragma unroll
        for (int r = 0; r < 4; ++r) {
            float mx = fmaxf(fmaxf(sacc[0][r], sacc[1][r]), fmaxf(sacc[2][r], sacc[3][r]));
#pragma unroll
            for (int off = 1; off < 16; off <<= 1) mx = fmaxf(mx, __shfl_xor(mx, off));
            const float nm = fmaxf(m_i[r], mx);
            alpha[r] = exp2f((m_i[r] - nm) * C);
            m_i[r] = nm;
            float sum = 0.f;
#pragma unroll
            for (int ct = 0; ct < 4; ++ct) {
                const float p = exp2f((sacc[ct][r] - nm) * C);
                sacc[ct][r] = p;
                sum += p;
            }
#pragma unroll
            for (int off = 1; off < 16; off <<= 1) sum += __shfl_xor(sum, off);
            l_i[r] = alpha[r] * l_i[r] + sum;
        }

        // --- P: C-layout -> A-layout via per-wave swizzled LDS scratch ---
        u16* ps = &Ps[wave][0];
#pragma unroll
        for (int ct = 0; ct < 4; ++ct)
#pragma unroll
            for (int r = 0; r < 4; ++r) {
                const int qq  = quad * 4 + r;
                const int col = ct * 16 + lm;
                ps[(qq * 8 + ((col >> 3) ^ (qq & 7))) * 8 + (col & 7)] = f2bf(sacc[ct][r]);
            }
        bf16x8 pf[2];
#pragma unroll
        for (int ks = 0; ks < 2; ++ks)
            pf[ks] = *(const bf16x8*)&ps[(lm * 8 + ((ks * 4 + quad) ^ (lm & 7))) * 8];

        // --- rescale O, then PV: O[16 q][128 d] += P[16][64] @ V[64][128] ---
#pragma unroll
        for (int dt = 0; dt < 8; ++dt)
#pragma unroll
            for (int r = 0; r < 4; ++r) acc_o[dt][r] *= alpha[r];

        __builtin_amdgcn_s_setprio(1);
#pragma unroll
        for (int ks = 0; ks < 2; ++ks)
#pragma unroll
            for (int dt = 0; dt < 8; ++dt) {
                const int d = dt * 16 + lm;
                bf16x8 vf = *(const bf16x8*)&vtb[(d * 8 + ((ks * 4 + quad) ^ (d & 7))) * 8];
                acc_o[dt] = __builtin_amdgcn_mfma_f32_16x16x32_bf16(pf[ks], vf, acc_o[dt], 0, 0, 0);
            }
        __builtin_amdgcn_s_setprio(0);

        // one barrier per tile: waits the prefetch (vmcnt) AND closes the
        // read window on buf[sel] before next iteration overwrites it
        if (kt < qt) __syncthreads();
    }

    // --- epilogue ---
    float inv_l[4];
#pragma unroll
    for (int r = 0; r < 4; ++r) inv_l[r] = 1.f / l_i[r];
    u16* op = ctx + ((size_t)(b * SEQLEN) + q0 + wave * 16 + quad * 4) * DIM + h * HEAD_DIM + lm;
#pragma unroll
    for (int r = 0; r < 4; ++r)
#pragma unroll
        for (int dt = 0; dt < 8; ++dt)
            op[(size_t)r * DIM + dt * 16] = f2bf(acc_o[dt][r] * inv_l[r]);
}

// ---------------------------------------------------------------------------
// kernel_launch
// ---------------------------------------------------------------------------
extern "C" void kernel_launch(void* const* d_in, const int* in_sizes, int n_in,
                              void* d_out, int out_size, void* d_ws, size_t ws_size,
                              hipStream_t stream) {
    const float* x   = (const float*)d_in[0];
    const float* wq  = (const float*)d_in[1];
    const float* wk  = (const float*)d_in[2];
    const float* wv  = (const float*)d_in[3];
    const float* wo  = (const float*)d_in[4];
    const float* fc  = (const float*)d_in[5];
    const float* fs  = (const float*)d_in[6];
    float* out = (float*)d_out;

    // ws carve-up: exactly 160 MiB total
    u16* x_bf = (u16*)d_ws;                       // [4096][4096]
    u16* wqT  = x_bf + (size_t)BS * DIM;          // [4096][4096]
    u16* wkT  = wqT + (size_t)DIM * DIM;          // [1024][4096]
    u16* wvT  = wkT + (size_t)KV_DIM * DIM;       // [1024][4096]
    u16* woT  = wvT + (size_t)KV_DIM * DIM;       // [4096][4096]
    u16* xq   = woT + (size_t)DIM * DIM;          // [4096][4096]
    u16* xk   = xq + (size_t)BS * DIM;            // [4096][1024]
    u16* xv   = xk + (size_t)BS * KV_DIM;         // [4096][1024]
    u16* ctx  = x_bf;                             // alias x_bf (dead after QKV GEMMs)
    u16* xvT  = wvT;                              // alias wvT (dead after V projection)

    // 0) converts
    {
        int n4 = BS * DIM / 4;
        cvt_f32_bf16<<<(n4 + 255) / 256, 256, 0, stream>>>(x, x_bf, n4);
        dim3 blk(32, 8);
        transpose_f32_bf16<<<dim3(DIM / 32, DIM / 32), blk, 0, stream>>>(wq, wqT, DIM, DIM);
        transpose_f32_bf16<<<dim3(KV_DIM / 32, DIM / 32), blk, 0, stream>>>(wk, wkT, DIM, KV_DIM);
        transpose_f32_bf16<<<dim3(KV_DIM / 32, DIM / 32), blk, 0, stream>>>(wv, wvT, DIM, KV_DIM);
        transpose_f32_bf16<<<dim3(DIM / 32, DIM / 32), blk, 0, stream>>>(wo, woT, DIM, DIM);
    }

    // 1) QKV projections (MFMA)
    gemm_mfma_bt<true><<<dim3(DIM / 128, BS / 128), 256, 0, stream>>>(x_bf, wqT, xq, BS, DIM, DIM);
    gemm_mfma_bt<true><<<dim3(KV_DIM / 128, BS / 128), 256, 0, stream>>>(x_bf, wkT, xk, BS, KV_DIM, DIM);
    gemm_mfma_bt<true><<<dim3(KV_DIM / 128, BS / 128), 256, 0, stream>>>(x_bf, wvT, xv, BS, KV_DIM, DIM);

    // 1b) V -> head-major transposed layout (overwrites dead wvT)
    transpose_v_bf16<<<dim3(SEQLEN / 32, HEAD_DIM / 32, BSZ * N_KV_HEADS), dim3(32, 8), 0, stream>>>(xv, xvT);

    // 2) RoPE (Q and K only)
    {
        int total_q = BS * N_HEADS * 64;
        rope_kernel<<<(total_q + 255) / 256, 256, 0, stream>>>(xq, fc, fs, N_HEADS, total_q);
        int total_k = BS * N_KV_HEADS * 64;
        rope_kernel<<<(total_k + 255) / 256, 256, 0, stream>>>(xk, fc, fs, N_KV_HEADS, total_k);
    }

    // 3) MFMA flash attention (Q-tile 64, double-buffered) -> bf16 ctx
    flash_attn_mfma<<<dim3(SEQLEN / 64, N_HEADS, BSZ), 256, 0, stream>>>(xq, xk, xvT, ctx);

    // 4) Output projection (MFMA) -> fp32 out
    gemm_mfma_bt<false><<<dim3(DIM / 128, BS / 128), 256, 0, stream>>>(ctx, woT, out, BS, DIM, DIM);
}

// Round 4
// 993.559 us; speedup vs baseline: 1.2896x; 1.1404x over previous
//
#include <hip/hip_runtime.h>
#include <hip/hip_bf16.h>
#include <math.h>
#include <stdint.h>

// Problem constants
#define DIM 4096
#define N_HEADS 32
#define N_KV_HEADS 8
#define HEAD_DIM 128
#define BSZ 2
#define SEQLEN 2048
#define BS (BSZ * SEQLEN)               // 4096 rows
#define KV_DIM (N_KV_HEADS * HEAD_DIM)  // 1024

typedef unsigned short u16;
typedef __attribute__((ext_vector_type(8))) short bf16x8;
typedef __attribute__((ext_vector_type(4))) float f32x4;
typedef __attribute__((ext_vector_type(16))) float f32x16;
typedef __attribute__((ext_vector_type(8))) unsigned short u16x8;
typedef __attribute__((ext_vector_type(4))) unsigned short u16x4;

__device__ __forceinline__ u16 f2bf(float f) {
    __hip_bfloat16 h = __float2bfloat16(f);
    return *reinterpret_cast<u16*>(&h);
}
__device__ __forceinline__ float bf2f(u16 u) {
    __hip_bfloat16 h;
    *reinterpret_cast<u16*>(&h) = u;
    return __bfloat162float(h);
}
__device__ __forceinline__ uint32_t packbf(float a, float b) {
    return (uint32_t)f2bf(a) | ((uint32_t)f2bf(b) << 16);
}

#define GLOAD_LDS16(gptr, lptr)                                                      \
    __builtin_amdgcn_global_load_lds(                                                \
        reinterpret_cast<const __attribute__((address_space(1))) uint32_t*>(         \
            reinterpret_cast<uintptr_t>(gptr)),                                      \
        reinterpret_cast<__attribute__((address_space(3))) uint32_t*>(               \
            reinterpret_cast<uintptr_t>(lptr)),                                      \
        16, 0, 0)

// ---------------------------------------------------------------------------
// cvt: fp32 -> bf16, 4 elems/thread
// ---------------------------------------------------------------------------
__global__ void cvt_f32_bf16(const float* __restrict__ in, u16* __restrict__ out, int n4) {
    int i = blockIdx.x * blockDim.x + threadIdx.x;
    if (i >= n4) return;
    float4 v = reinterpret_cast<const float4*>(in)[i];
    u16x4 o;
    o.x = f2bf(v.x); o.y = f2bf(v.y); o.z = f2bf(v.z); o.w = f2bf(v.w);
    reinterpret_cast<u16x4*>(out)[i] = o;
}

// ---------------------------------------------------------------------------
// transpose + cvt: in[K][N] fp32 -> out[N][K] bf16.  block (32,8), 32x32 tile.
// ---------------------------------------------------------------------------
__global__ __launch_bounds__(256) void transpose_f32_bf16(const float* __restrict__ in,
                                                          u16* __restrict__ out,
                                                          int K, int N) {
    __shared__ float tile[32][33];
    const int tx = threadIdx.x, ty = threadIdx.y;
    const int n0 = blockIdx.x * 32, k0 = blockIdx.y * 32;
#pragma unroll
    for (int i = 0; i < 4; ++i)
        tile[ty + 8 * i][tx] = in[(size_t)(k0 + ty + 8 * i) * N + n0 + tx];
    __syncthreads();
#pragma unroll
    for (int i = 0; i < 4; ++i)
        out[(size_t)(n0 + ty + 8 * i) * K + k0 + tx] = f2bf(tile[tx][ty + 8 * i]);
}

// ---------------------------------------------------------------------------
// transpose bf16 V into per-(b,hkv) head-major layout:
//   xv  [BS][KV_DIM]  (row = b*S + k, col = hkv*128 + d)
//   xvT [(b*8+hkv)*128 + d][SEQLEN]  (col = k)
// ---------------------------------------------------------------------------
__global__ __launch_bounds__(256) void transpose_v_bf16(const u16* __restrict__ xv,
                                                        u16* __restrict__ xvT) {
    __shared__ u16 tile[32][33];
    const int tx = threadIdx.x, ty = threadIdx.y;
    const int k0 = blockIdx.x * 32, d0 = blockIdx.y * 32;
    const int bh = blockIdx.z;
    const int b = bh >> 3, hkv = bh & 7;
#pragma unroll
    for (int i = 0; i < 4; ++i)
        tile[ty + 8 * i][tx] =
            xv[((size_t)(b * SEQLEN) + k0 + ty + 8 * i) * KV_DIM + hkv * HEAD_DIM + d0 + tx];
    __syncthreads();
#pragma unroll
    for (int i = 0; i < 4; ++i)
        xvT[((size_t)bh * HEAD_DIM + d0 + ty + 8 * i) * SEQLEN + k0 + tx] = tile[tx][ty + 8 * i];
}

// ---------------------------------------------------------------------------
// MFMA bf16 GEMM:  C[M,N] = A[M,K] @ B[K,N]  with B given TRANSPOSED (BT[N,K]).
// (unchanged — verified good)
// ---------------------------------------------------------------------------
template <bool OUT_BF16>
__global__ __launch_bounds__(256) void gemm_mfma_bt(const u16* __restrict__ A,
                                                    const u16* __restrict__ BT,
                                                    void* __restrict__ Cv,
                                                    int M, int N, int K) {
    __shared__ __align__(16) u16 Al[128 * 64];
    __shared__ __align__(16) u16 Bl[128 * 64];

    const int tid  = threadIdx.x;
    const int wave = tid >> 6;
    const int lane = tid & 63;
    const int quad = lane >> 4;
    const int lm   = lane & 15;
    const size_t bm = (size_t)blockIdx.y * 128;
    const size_t bn = (size_t)blockIdx.x * 128;
    const int wm = (wave & 1) * 64;
    const int wn = (wave >> 1) * 64;

    const int slot = lane & 7;
    const int lrow = lane >> 3;
    const int csw  = slot ^ (lrow & 7);

    f32x4 acc[4][4] = {};

    for (int k0 = 0; k0 < K; k0 += 64) {
        __syncthreads();
#pragma unroll
        for (int i = 0; i < 4; ++i) {
            const int mloc = wave * 32 + i * 8 + lrow;
            const u16* gA = A  + (bm + mloc) * (size_t)K + k0 + csw * 8;
            const u16* gB = BT + (bn + mloc) * (size_t)K + k0 + csw * 8;
            u16* lA = &Al[(mloc * 8 + slot) * 8];
            u16* lB = &Bl[(mloc * 8 + slot) * 8];
            GLOAD_LDS16(gA, lA);
            GLOAD_LDS16(gB, lB);
        }
        __syncthreads();

#pragma unroll
        for (int ks8 = 0; ks8 < 8; ks8 += 4) {
            bf16x8 af[4], bfr[4];
            const int cc = ks8 + quad;
#pragma unroll
            for (int i = 0; i < 4; ++i) {
                const int m = wm + 16 * i + lm;
                af[i]  = *(const bf16x8*)&Al[(m * 8 + (cc ^ (m & 7))) * 8];
                const int n = wn + 16 * i + lm;
                bfr[i] = *(const bf16x8*)&Bl[(n * 8 + (cc ^ (n & 7))) * 8];
            }
#pragma unroll
            for (int i = 0; i < 4; ++i)
#pragma unroll
                for (int j = 0; j < 4; ++j)
                    acc[i][j] = __builtin_amdgcn_mfma_f32_16x16x32_bf16(af[i], bfr[j], acc[i][j], 0, 0, 0);
        }
    }

#pragma unroll
    for (int i = 0; i < 4; ++i) {
        const int mrow = wm + 16 * i + quad * 4;
#pragma unroll
        for (int j = 0; j < 4; ++j) {
            const int ncol = wn + 16 * j + lm;
#pragma unroll
            for (int r = 0; r < 4; ++r) {
                const size_t off = (bm + mrow + r) * (size_t)N + bn + ncol;
                const float v = acc[i][j][r];
                if constexpr (OUT_BF16) ((u16*)Cv)[off] = f2bf(v);
                else                    ((float*)Cv)[off] = v;
            }
        }
    }
}

// ---------------------------------------------------------------------------
// RoPE (interleaved pairs), in-place on bf16. t layout: (BS, n_heads*128).
// ---------------------------------------------------------------------------
__global__ void rope_kernel(u16* __restrict__ t,
                            const float* __restrict__ cosb,
                            const float* __restrict__ sinb,
                            int n_heads, int total_pairs) {
    int idx = blockIdx.x * blockDim.x + threadIdx.x;
    if (idx >= total_pairs) return;
    int p = idx & 63;
    int h = (idx >> 6) % n_heads;
    int bs = idx / (64 * n_heads);
    int s = bs & (SEQLEN - 1);        // start_pos = 0

    float c = cosb[s * 64 + p];
    float sn = sinb[s * 64 + p];

    size_t base = (size_t)bs * (n_heads * HEAD_DIM) + h * HEAD_DIM + 2 * p;
    float e = bf2f(t[base]);
    float o = bf2f(t[base + 1]);
    t[base]     = f2bf(e * c - o * sn);
    t[base + 1] = f2bf(e * sn + o * c);
}

// ---------------------------------------------------------------------------
// MFMA flash attention — 32x32x16, swapped QK^T, in-register softmax.
//   grid (S/128, N_HEADS, BSZ) heavy-first, 256 threads = 4 waves.
//   Wave w owns q rows [128*qt + 32w, +32); lane's q = base + (lane&31).
//   KVBLK=64; K LDS [64][128], V^T LDS [128][64], chunk-XOR swizzled src.
//
//   QK^T swapped:  S^T = mfma(A=K, B=Q)  ->  C: col=lane&31 = q (LANE-LOCAL),
//     row = k = (reg&3)+8*(reg>>2)+4*(lane>>5).  Softmax reduce = in-register
//     over 32 regs + ONE shfl_xor(32) with the partner lane.
//   P -> PV A/B frag: pack f32 pairs to bf16 words, exchange 2 words per
//     16-k slice with partner via shfl_xor(32) (8 shuffles/tile). No P LDS.
//   PV: O^T = mfma(A=V^T, B=P^T) -> col=lane&31 = q again: alpha-rescale and
//     1/l are scalar per lane.  O^T transposed via LDS (after K/V dead) for
//     coalesced stores.
// Fragment layouts (32x32x16): A row=lane&31, k=(lane>>5)*8+j; B k=(lane>>5)*8+j,
//   col=lane&31; C col=lane&31, row=(reg&3)+8*(reg>>2)+4*(lane>>5). [m74/m101]
// ---------------------------------------------------------------------------
#define OPAD 132   // O-stage row stride (u16): 264B -> 2-way (free) bank pattern

__global__ __launch_bounds__(256, 2) void flash_attn_mfma(const u16* __restrict__ xq,
                                                          const u16* __restrict__ xk,
                                                          const u16* __restrict__ xvT,
                                                          u16* __restrict__ ctx) {
    __shared__ __align__(16) u16 LB[128 * OPAD];   // 33792 B; Ks/Vt overlay + O-stage
    u16* Ks = LB;                  // [64 k][16 chunks][8]  = 8192 u16
    u16* Vt = LB + 64 * 16 * 8;    // [128 d][8 chunks][8]  = 8192 u16

    const int qt  = (int)gridDim.x - 1 - (int)blockIdx.x;  // heavy-first
    const int h   = blockIdx.y;
    const int b   = blockIdx.z;
    const int hkv = h >> 2;

    const int tid  = threadIdx.x;
    const int wave = tid >> 6;
    const int lane = tid & 63;
    const int hh   = lane >> 5;         // half (0/1)
    const int l31  = lane & 31;
    const int q0   = qt * 128;
    const int wq0  = q0 + wave * 32;
    const int qrow = wq0 + l31;         // this lane's q row (in seq)
    const float C = 0.08838834764831845f * 1.44269504088896f;  // (1/sqrt(128))*log2(e)

    // Q fragments (B-operand): qf[step] = Q[qrow][16*step + 8*hh .. +8]
    bf16x8 qf[8];
    {
        const u16* qp = xq + ((size_t)(b * SEQLEN) + qrow) * DIM + h * HEAD_DIM + hh * 8;
#pragma unroll
        for (int s = 0; s < 8; ++s) qf[s] = *(const bf16x8*)(qp + 16 * s);
    }

    const u16* xkb = xk + (size_t)(b * SEQLEN) * KV_DIM + hkv * HEAD_DIM;
    const u16* xvb = xvT + ((size_t)(b * N_KV_HEADS + hkv)) * HEAD_DIM * SEQLEN;

    float m_i = -INFINITY, l_i = 0.f;
    f32x16 acc[4] = {};   // acc[dt]: O^T, d = 32*dt + (reg&3)+8*(reg>>2)+4*hh, col q = qrow

    const int nkt = 2 * qt + 2;
    for (int kt = 0; kt < nkt; ++kt) {
        const int k0 = kt * 64;
        __syncthreads();
        // --- stage K [64][128] and V^T [128][64]; src chunk-XOR pre-swizzled ---
#pragma unroll
        for (int i = 0; i < 4; ++i) {
            const int ci = i * 256 + tid;            // 0..1023
            const int kr = ci >> 4, cp = ci & 15;
            GLOAD_LDS16(xkb + (size_t)(k0 + kr) * KV_DIM + (cp ^ (kr & 7)) * 8, &Ks[ci * 8]);
            const int dr = ci >> 3, cq = ci & 7;
            GLOAD_LDS16(xvb + (size_t)dr * SEQLEN + k0 + (cq ^ (dr & 7)) * 8, &Vt[ci * 8]);
        }
        __syncthreads();

        if (k0 > wq0 + 31) continue;   // fully masked for this wave (stage already done)

        // --- QK^T (swapped): s[ct] = S^T[k=32ct.., q] ---
        f32x16 s[2] = {};
        __builtin_amdgcn_s_setprio(1);
#pragma unroll
        for (int step = 0; step < 8; ++step) {
#pragma unroll
            for (int ct = 0; ct < 2; ++ct) {
                const int krow = ct * 32 + l31;
                const int c = 2 * step + hh;
                bf16x8 kf = *(const bf16x8*)&Ks[(krow * 16 + (c ^ (krow & 7))) * 8];
                s[ct] = __builtin_amdgcn_mfma_f32_32x32x16_bf16(kf, qf[step], s[ct], 0, 0, 0);
            }
        }
        __builtin_amdgcn_s_setprio(0);

        // --- causal mask (raw-score domain); only near-diagonal tiles ---
        if (k0 + 63 > wq0) {
#pragma unroll
            for (int ct = 0; ct < 2; ++ct)
#pragma unroll
                for (int r = 0; r < 16; ++r) {
                    const int kg = k0 + ct * 32 + (r & 3) + 8 * (r >> 2) + 4 * hh;
                    if (kg > qrow) s[ct][r] = -1e30f;
                }
        }

        // --- online softmax: lane-local reduce + one partner exchange ---
        float mx = s[0][0];
#pragma unroll
        for (int r = 1; r < 16; ++r) mx = fmaxf(mx, s[0][r]);
#pragma unroll
        for (int r = 0; r < 16; ++r) mx = fmaxf(mx, s[1][r]);
        mx = fmaxf(mx, __shfl_xor(mx, 32));
        const float nm = fmaxf(m_i, mx);
        const float alpha = exp2f((m_i - nm) * C);
        m_i = nm;
        float sum = 0.f;
#pragma unroll
        for (int ct = 0; ct < 2; ++ct)
#pragma unroll
            for (int r = 0; r < 16; ++r) {
                const float p = exp2f((s[ct][r] - nm) * C);
                s[ct][r] = p;
                sum += p;
            }
        sum += __shfl_xor(sum, 32);
        l_i = alpha * l_i + sum;

        // --- P -> PV B-operand frags, in-register (partner word exchange) ---
        bf16x8 pa[4];
#pragma unroll
        for (int ct = 0; ct < 2; ++ct)
#pragma unroll
            for (int kss = 0; kss < 2; ++kss) {
                const int base = 8 * kss;
                const uint32_t lo0 = packbf(s[ct][base + 0], s[ct][base + 1]);
                const uint32_t lo1 = packbf(s[ct][base + 2], s[ct][base + 3]);
                const uint32_t hi0 = packbf(s[ct][base + 4], s[ct][base + 5]);
                const uint32_t hi1 = packbf(s[ct][base + 6], s[ct][base + 7]);
                const uint32_t s0 = hh ? lo0 : hi0;
                const uint32_t s1 = hh ? lo1 : hi1;
                const uint32_t r0 = (uint32_t)__shfl_xor((int)s0, 32);
                const uint32_t r1 = (uint32_t)__shfl_xor((int)s1, 32);
                union { uint32_t u[4]; bf16x8 v; } pu;
                pu.u[0] = hh ? r0 : lo0;
                pu.u[1] = hh ? r1 : lo1;
                pu.u[2] = hh ? hi0 : r0;
                pu.u[3] = hh ? hi1 : r1;
                pa[2 * ct + kss] = pu.v;
            }

        // --- rescale O (lane-local alpha), then PV: O^T = mfma(V^T, P^T) ---
#pragma unroll
        for (int dt = 0; dt < 4; ++dt)
#pragma unroll
            for (int r = 0; r < 16; ++r) acc[dt][r] *= alpha;

        __builtin_amdgcn_s_setprio(1);
#pragma unroll
        for (int ks = 0; ks < 4; ++ks)
#pragma unroll
            for (int dt = 0; dt < 4; ++dt) {
                const int vrow = dt * 32 + l31;
                const int c = 2 * ks + hh;
                bf16x8 vf = *(const bf16x8*)&Vt[(vrow * 8 + (c ^ (vrow & 7))) * 8];
                acc[dt] = __builtin_amdgcn_mfma_f32_32x32x16_bf16(vf, pa[ks], acc[dt], 0, 0, 0);
            }
        __builtin_amdgcn_s_setprio(0);
    }

    // --- epilogue: O^T regs -> LDS [q][OPAD] -> coalesced global stores ---
    __syncthreads();                        // K/V reads complete block-wide
    const float inv_l = 1.0f / l_i;
    const int q_l = wave * 32 + l31;
#pragma unroll
    for (int dt = 0; dt < 4; ++dt)
#pragma unroll
        for (int rp = 0; rp < 8; ++rp) {
            const int reg = 2 * rp;
            const int d = dt * 32 + (reg & 3) + 8 * (reg >> 2) + 4 * hh;
            *(uint32_t*)&LB[q_l * OPAD + d] =
                packbf(acc[dt][reg] * inv_l, acc[dt][reg + 1] * inv_l);
        }
    __syncthreads();
    {
        const int qr = tid >> 1, hf = tid & 1;
        u16* op = ctx + ((size_t)(b * SEQLEN) + q0 + qr) * DIM + h * HEAD_DIM + hf * 64;
        const u16* lp = &LB[qr * OPAD + hf * 64];
#pragma unroll
        for (int c = 0; c < 16; ++c)
            *(u16x4*)(op + 4 * c) = *(const u16x4*)(lp + 4 * c);
    }
}

// ---------------------------------------------------------------------------
// kernel_launch
// ---------------------------------------------------------------------------
extern "C" void kernel_launch(void* const* d_in, const int* in_sizes, int n_in,
                              void* d_out, int out_size, void* d_ws, size_t ws_size,
                              hipStream_t stream) {
    const float* x   = (const float*)d_in[0];
    const float* wq  = (const float*)d_in[1];
    const float* wk  = (const float*)d_in[2];
    const float* wv  = (const float*)d_in[3];
    const float* wo  = (const float*)d_in[4];
    const float* fc  = (const float*)d_in[5];
    const float* fs  = (const float*)d_in[6];
    float* out = (float*)d_out;

    // ws carve-up: exactly 160 MiB total
    u16* x_bf = (u16*)d_ws;                       // [4096][4096]
    u16* wqT  = x_bf + (size_t)BS * DIM;          // [4096][4096]
    u16* wkT  = wqT + (size_t)DIM * DIM;          // [1024][4096]
    u16* wvT  = wkT + (size_t)KV_DIM * DIM;       // [1024][4096]
    u16* woT  = wvT + (size_t)KV_DIM * DIM;       // [4096][4096]
    u16* xq   = woT + (size_t)DIM * DIM;          // [4096][4096]
    u16* xk   = xq + (size_t)BS * DIM;            // [4096][1024]
    u16* xv   = xk + (size_t)BS * KV_DIM;         // [4096][1024]
    u16* ctx  = x_bf;                             // alias x_bf (dead after QKV GEMMs)
    u16* xvT  = wvT;                              // alias wvT (dead after V projection)

    // 0) converts
    {
        int n4 = BS * DIM / 4;
        cvt_f32_bf16<<<(n4 + 255) / 256, 256, 0, stream>>>(x, x_bf, n4);
        dim3 blk(32, 8);
        transpose_f32_bf16<<<dim3(DIM / 32, DIM / 32), blk, 0, stream>>>(wq, wqT, DIM, DIM);
        transpose_f32_bf16<<<dim3(KV_DIM / 32, DIM / 32), blk, 0, stream>>>(wk, wkT, DIM, KV_DIM);
        transpose_f32_bf16<<<dim3(KV_DIM / 32, DIM / 32), blk, 0, stream>>>(wv, wvT, DIM, KV_DIM);
        transpose_f32_bf16<<<dim3(DIM / 32, DIM / 32), blk, 0, stream>>>(wo, woT, DIM, DIM);
    }

    // 1) QKV projections (MFMA)
    gemm_mfma_bt<true><<<dim3(DIM / 128, BS / 128), 256, 0, stream>>>(x_bf, wqT, xq, BS, DIM, DIM);
    gemm_mfma_bt<true><<<dim3(KV_DIM / 128, BS / 128), 256, 0, stream>>>(x_bf, wkT, xk, BS, KV_DIM, DIM);
    gemm_mfma_bt<true><<<dim3(KV_DIM / 128, BS / 128), 256, 0, stream>>>(x_bf, wvT, xv, BS, KV_DIM, DIM);

    // 1b) V -> head-major transposed layout (overwrites dead wvT)
    transpose_v_bf16<<<dim3(SEQLEN / 32, HEAD_DIM / 32, BSZ * N_KV_HEADS), dim3(32, 8), 0, stream>>>(xv, xvT);

    // 2) RoPE (Q and K only)
    {
        int total_q = BS * N_HEADS * 64;
        rope_kernel<<<(total_q + 255) / 256, 256, 0, stream>>>(xq, fc, fs, N_HEADS, total_q);
        int total_k = BS * N_KV_HEADS * 64;
        rope_kernel<<<(total_k + 255) / 256, 256, 0, stream>>>(xk, fc, fs, N_KV_HEADS, total_k);
    }

    // 3) MFMA flash attention (32x32, swapped QK^T, Q-tile 128) -> bf16 ctx
    flash_attn_mfma<<<dim3(SEQLEN / 128, N_HEADS, BSZ), 256, 0, stream>>>(xq, xk, xvT, ctx);

    // 4) Output projection (MFMA) -> fp32 out
    gemm_mfma_bt<false><<<dim3(DIM / 128, BS / 128), 256, 0, stream>>>(ctx, woT, out, BS, DIM, DIM);
}